// Round 2
// baseline (197.027 us; speedup 1.0000x reference)
//
#include <hip/hip_runtime.h>

// GTConv autoencoder on the product graph, MI355X.
// Structure: S = It (x) Ag + St (x) Bg with Ag = s00 I + s01 Sg, Bg = s10 I + s11 Sg.
// => S^k x [t] = sum_{d,p<=k} c[k][d][p] * Sg^p x[t-d]  (cyclic in t).
// Conv output: Y[t,m,o] = sum_i sum_{d,p} g[o,i,d,p] * Zp[t-d, m, i],
//   g[o,i,d,p] = sum_k h[o,i,k] c[k][d][p],  Z0 = x, Z1 = Sg x, Z2 = Sg^2 x.
// Node dim never mixes outside Sg => combine is pointwise in m.
//
// Buffers layout in ws (floats):
//   SgT   @ 0       (192*192)  transposed Sg  (for coalesced GEMV)
//   Sg2T  @ 36864   (192*192)  transposed Sg^2
//   g_e1  @ 73728   (144)
//   g_e2  @ 73872   (4608)
//   g_d1  @ 78480   (4608)
//   g_d2  @ 83088   (144)
//   Z1    @ 83232   (98304)    [t][i][m]
//   Z2    @ 181536  (98304)
//   buf1  @ 279840  (16*16*192) e1 out, after down+relu   [q][o][m]
//   buf2  @ 328992  (8*32*192)  e2 out, after down+relu
//   buf3  @ 378144  (16*16*192) d1 conv out (raw)

#define NODES 192

__device__ __forceinline__ void compute_c(const float* __restrict__ s, float c[3][3][3]) {
    const float s00 = s[0], s01 = s[1], s10 = s[2], s11 = s[3];
    #pragma unroll
    for (int k = 0; k < 3; ++k)
        #pragma unroll
        for (int d = 0; d < 3; ++d)
            #pragma unroll
            for (int p = 0; p < 3; ++p) c[k][d][p] = 0.f;
    c[0][0][0] = 1.f;
    c[1][0][0] = s00; c[1][0][1] = s01;
    c[1][1][0] = s10; c[1][1][1] = s11;
    c[2][0][0] = s00 * s00;             c[2][0][1] = 2.f * s00 * s01;                  c[2][0][2] = s01 * s01;
    c[2][1][0] = 2.f * s00 * s10;       c[2][1][1] = 2.f * (s00 * s11 + s01 * s10);    c[2][1][2] = 2.f * s01 * s11;
    c[2][2][0] = s10 * s10;             c[2][2][1] = 2.f * s10 * s11;                  c[2][2][2] = s11 * s11;
}

// Prep: SgT, Sg2T (transposed so GEMV reads coalesce over m), g tables.
__global__ __launch_bounds__(256) void prep_kernel(
        const float* __restrict__ Sg, const float* __restrict__ s,
        const float* __restrict__ he1, const float* __restrict__ he2,
        const float* __restrict__ hd1, const float* __restrict__ hd2,
        float* __restrict__ ws) {
    const int b = blockIdx.x, tid = threadIdx.x;
    float* SgT  = ws;
    float* Sg2T = ws + 36864;
    if (b < 144) {                       // transpose Sg
        int idx = b * 256 + tid;         // [0, 36864)
        int n = idx / NODES, m = idx % NODES;
        SgT[n * NODES + m] = Sg[m * NODES + n];
    } else if (b < 288) {                // Sg2T[n][m] = (Sg*Sg)[m][n]
        int idx = (b - 144) * 256 + tid;
        int n = idx / NODES, m = idx % NODES;
        float acc = 0.f;
        for (int r = 0; r < NODES; ++r) acc += Sg[m * NODES + r] * Sg[r * NODES + n];
        Sg2T[n * NODES + m] = acc;
    } else {                             // g tables
        float c[3][3][3];
        compute_c(s, c);
        float* g = ws + 73728;
        const float* hs[4] = {he1, he2, hd1, hd2};
        const int cin[4]  = {1, 16, 32, 16};
        const int cout[4] = {16, 32, 16, 1};
        int base = 0;
        for (int l = 0; l < 4; ++l) {
            const int sz = cout[l] * cin[l] * 9;
            for (int idx = tid; idx < sz; idx += 256) {
                int o = idx / (cin[l] * 9);
                int rem = idx % (cin[l] * 9);
                int i = rem / 9, dp = rem % 9, d = dp / 3, p = dp % 3;
                float acc = 0.f;
                for (int k = 0; k < 3; ++k)
                    acc += hs[l][(o * cin[l] + i) * 3 + k] * c[k][d][p];
                g[base + idx] = acc;
            }
            base += sz;
        }
    }
}

// Input readers. Value of layer input at (time t, channel i, node n).
// INMODE 0: X (192x32 row-major), i==0.
// INMODE 1: plain buffer [t][i][n] (already activated).
// INMODE 2: zero-stuffed upsample + relu from buffer [t/2][i][n].
template <int CIN, int INMODE>
__device__ __forceinline__ float read_in(const float* __restrict__ src, int t, int i, int n) {
    if (INMODE == 0) return src[n * 32 + t];
    if (INMODE == 1) return src[(t * CIN + i) * NODES + n];
    // INMODE == 2
    if (t & 1) return 0.f;
    return fmaxf(src[((t >> 1) * CIN + i) * NODES + n], 0.f);
}

// Z kernel: Z1[t][i][m] = sum_n Sg[m][n] x[t][i][n];  Z2 with Sg^2.
// Grid: T * (CIN/IB) blocks of 192 threads (thread = node m).
template <int T, int CIN, int IB, int INMODE>
__global__ __launch_bounds__(192) void zker(
        const float* __restrict__ src,
        const float* __restrict__ SgT, const float* __restrict__ Sg2T,
        float* __restrict__ Z1, float* __restrict__ Z2) {
    const int bx = blockIdx.x;
    const int t = bx % T, i0 = (bx / T) * IB;
    const int m = threadIdx.x;
    if (INMODE == 2 && (t & 1)) {        // upsampled zeros propagate
        #pragma unroll
        for (int i = 0; i < IB; ++i) {
            Z1[(t * CIN + i0 + i) * NODES + m] = 0.f;
            Z2[(t * CIN + i0 + i) * NODES + m] = 0.f;
        }
        return;
    }
    __shared__ float xs[IB][193];
    for (int idx = m; idx < IB * NODES; idx += NODES) {
        int i = idx / NODES, n = idx % NODES;
        xs[i][n] = read_in<CIN, INMODE>(src, t, i0 + i, n);
    }
    __syncthreads();
    float a1[IB], a2[IB];
    #pragma unroll
    for (int i = 0; i < IB; ++i) { a1[i] = 0.f; a2[i] = 0.f; }
    for (int n = 0; n < NODES; ++n) {
        float sa = SgT[n * NODES + m];   // coalesced over lanes
        float sb = Sg2T[n * NODES + m];
        #pragma unroll
        for (int i = 0; i < IB; ++i) {
            float xv = xs[i][n];         // broadcast
            a1[i] += sa * xv;
            a2[i] += sb * xv;
        }
    }
    #pragma unroll
    for (int i = 0; i < IB; ++i) {
        Z1[(t * CIN + i0 + i) * NODES + m] = a1[i];
        Z2[(t * CIN + i0 + i) * NODES + m] = a2[i];
    }
}

// Combine kernel: Y[t][m][o] = sum_i sum_{d,p} g[o][i][d][p] * Zp[t-d][i][m].
// OUTMODE 0: encoder: block owns out-time q, computes conv times 2q,2q+1, max+relu -> out[q][o][m]
// OUTMODE 1: decoder raw store -> out[t][o][m]
// OUTMODE 2: final: out[m*32 + t], COUT == 1
template <int T, int CIN, int COUT, int OB, int INMODE, int OUTMODE>
__global__ __launch_bounds__(192) void cker(
        const float* __restrict__ src,
        const float* __restrict__ Z1, const float* __restrict__ Z2,
        const float* __restrict__ g, float* __restrict__ out) {
    const int bx = blockIdx.x;
    const int TQ = (OUTMODE == 0) ? T / 2 : T;
    const int tq = bx % TQ, o0 = (bx / TQ) * OB;
    const int m = threadIdx.x;
    __shared__ float gs[OB][CIN][9];
    for (int idx = m; idx < OB * CIN * 9; idx += NODES) {
        int o = idx / (CIN * 9), rem = idx % (CIN * 9);
        gs[o][rem / 9][rem % 9] = g[(o0 + o) * CIN * 9 + rem];
    }
    __syncthreads();
    const int nt = (OUTMODE == 0) ? 2 : 1;
    float res[2][OB];
    for (int tt = 0; tt < nt; ++tt) {
        const int t = (OUTMODE == 0) ? tq * 2 + tt : tq;
        float acc[OB];
        #pragma unroll
        for (int o = 0; o < OB; ++o) acc[o] = 0.f;
        for (int i = 0; i < CIN; ++i) {
            float z[3][3];
            #pragma unroll
            for (int d = 0; d < 3; ++d) {
                int td = t - d; if (td < 0) td += T;
                z[d][0] = read_in<CIN, INMODE>(src, td, i, m);
                z[d][1] = Z1[(td * CIN + i) * NODES + m];
                z[d][2] = Z2[(td * CIN + i) * NODES + m];
            }
            #pragma unroll
            for (int o = 0; o < OB; ++o) {
                float a = acc[o];
                #pragma unroll
                for (int d = 0; d < 3; ++d)
                    #pragma unroll
                    for (int p = 0; p < 3; ++p)
                        a += gs[o][i][d * 3 + p] * z[d][p];
                acc[o] = a;
            }
        }
        #pragma unroll
        for (int o = 0; o < OB; ++o) res[tt][o] = acc[o];
    }
    if (OUTMODE == 0) {
        #pragma unroll
        for (int o = 0; o < OB; ++o)
            out[(tq * COUT + o0 + o) * NODES + m] = fmaxf(fmaxf(res[0][o], res[1][o]), 0.f);
    } else if (OUTMODE == 1) {
        #pragma unroll
        for (int o = 0; o < OB; ++o)
            out[(tq * COUT + o0 + o) * NODES + m] = res[0][o];
    } else {
        out[m * 32 + tq] = res[0][0];
    }
}

extern "C" void kernel_launch(void* const* d_in, const int* in_sizes, int n_in,
                              void* d_out, int out_size, void* d_ws, size_t ws_size,
                              hipStream_t stream) {
    (void)in_sizes; (void)n_in; (void)out_size; (void)ws_size;
    const float* X   = (const float*)d_in[0];
    const float* Sg  = (const float*)d_in[1];
    const float* s   = (const float*)d_in[2];
    const float* he1 = (const float*)d_in[3];
    const float* he2 = (const float*)d_in[4];
    const float* hd1 = (const float*)d_in[5];
    const float* hd2 = (const float*)d_in[6];
    float* out = (float*)d_out;
    float* ws  = (float*)d_ws;

    float* SgT  = ws;
    float* Sg2T = ws + 36864;
    float* g_e1 = ws + 73728;
    float* g_e2 = ws + 73872;
    float* g_d1 = ws + 78480;
    float* g_d2 = ws + 83088;
    float* Z1   = ws + 83232;
    float* Z2   = ws + 181536;
    float* buf1 = ws + 279840;
    float* buf2 = ws + 328992;
    float* buf3 = ws + 378144;

    prep_kernel<<<289, 256, 0, stream>>>(Sg, s, he1, he2, hd1, hd2, ws);

    // L1 (e1): t=32, 1->16, down+relu
    zker<32, 1, 1, 0><<<32, 192, 0, stream>>>(X, SgT, Sg2T, Z1, Z2);
    cker<32, 1, 16, 16, 0, 0><<<16, 192, 0, stream>>>(X, Z1, Z2, g_e1, buf1);
    // L2 (e2): t=16, 16->32, down+relu
    zker<16, 16, 4, 1><<<64, 192, 0, stream>>>(buf1, SgT, Sg2T, Z1, Z2);
    cker<16, 16, 32, 8, 1, 0><<<32, 192, 0, stream>>>(buf1, Z1, Z2, g_e2, buf2);
    // L3 (d1): t=16, 32->16, input = relu(up(buf2)), raw out
    zker<16, 32, 4, 2><<<128, 192, 0, stream>>>(buf2, SgT, Sg2T, Z1, Z2);
    cker<16, 32, 16, 8, 2, 1><<<32, 192, 0, stream>>>(buf2, Z1, Z2, g_d1, buf3);
    // L4 (d2): t=32, 16->1, input = relu(up(buf3)), final transposed store
    zker<32, 16, 4, 2><<<128, 192, 0, stream>>>(buf3, SgT, Sg2T, Z1, Z2);
    cker<32, 16, 1, 1, 2, 2><<<32, 192, 0, stream>>>(buf3, Z1, Z2, g_d2, out);
}